// Round 13
// baseline (323.155 us; speedup 1.0000x reference)
//
#include <hip/hip_runtime.h>
#include <hip/hip_bf16.h>
#include <hip/hip_cooperative_groups.h>

// MPNScoreModule: B=8 graphs, N=64 nodes, E=256 edges, L=128, S=2 steps.
// Round 13: single cooperative kernel = prep (44 block-roles, pre-sync, LDS
// scratch aliased onto the main pool) + grid.sync() + round-12 main body,
// with 256 blocks each handling (g, d-pair) -> removes one kernel launch and
// the prep->main stream drain from the serial timeline. GEMM structure is
// round-12's proven 42.8us variant (prefetched A-frags, 4x B-reuse, merged
// barrier segments) -- untouched.

namespace cg = cooperative_groups;

typedef __attribute__((ext_vector_type(8))) __bf16 bf16x8;
typedef __attribute__((ext_vector_type(4))) __bf16 bf16x4;
typedef __attribute__((ext_vector_type(4))) float  floatx4;

#define MFMA16(a, b, c) __builtin_amdgcn_mfma_f32_16x16x32_bf16((a), (b), (c), 0, 0, 0)

__device__ __forceinline__ float leaky(float x) { return x > 0.f ? x : 0.01f * x; }

// ---- workspace layout (bytes) ----
#define WS_WT     0          // bf16 [10][16384] PACKED weights: [m][(mq*4+c)*64+l][8]
#define WS_XAP    327680     // f32  [8][64][128]  x @ Wne[0:128] + b_node_enc
#define WS_XDP    589824     // f32  [8][64][128]  x @ Wne[128:256]
#define WS_EE0    851968     // bf16 [8][256][128] leaky(edge_attr @ Wee + b)
#define WS_CE     1376256    // f32  [8][2][128]   gg @ W4  + b_edge_upd
#define WS_CN     1384448    // f32  [8][2][128]   gg @ Wn3 + b_node_upd
#define WS_CSROFF 1392640    // int  [8][72]
#define WS_CSREID 1394944    // int  [8][256]

#define LDE 140   // padded LDS row stride: 280 B = 70 dw = 6 mod 32 -> conflict-free

__global__ __launch_bounds__(512, 2) void mpn_fused(
    const float* __restrict__ x,     // [8][64][128]
    const float* __restrict__ ea,    // [8][256][128]
    const float* __restrict__ u,     // [8][128]
    const float* __restrict__ spdist,// [8][64][64]
    const int*   __restrict__ eidx,  // [8][2][256]
    const float* __restrict__ Wne,   // [257][128]
    const float* __restrict__ bne,   // [128]
    const float* __restrict__ Wee,   // [128][128]
    const float* __restrict__ bee,   // [128]
    const float* __restrict__ Wge,   // [128][128]
    const float* __restrict__ bge,   // [128]
    const float* __restrict__ Weu,   // [2][512][128]
    const float* __restrict__ beu,   // [2][128]
    const float* __restrict__ Wnu,   // [2][384][128]
    const float* __restrict__ bnu,   // [2][128]
    const float* __restrict__ wscore,// [128]
    const float* __restrict__ bscore,// [1]
    char* __restrict__ ws,
    float* __restrict__ out)         // [8][256][64]  (g*16384 + e*64 + d), fp32
{
  // one pool: main carves s_ee/s_h/s_p2/s_p3; prep aliases scratch pre-sync
  __shared__ __align__(16) __bf16 pool[448 * LDE];
  __shared__ int s_off[65];
  __shared__ int s_eid[256];
  __shared__ float s_sc[256];

  __bf16* s_ee = pool;               // [256][LDE]
  __bf16* s_h  = pool + 256*LDE;     // [64][LDE]
  __bf16* s_p2 = pool + 320*LDE;     // [64][LDE]
  __bf16* s_p3 = pool + 384*LDE;     // [64][LDE]

  __bf16* wt   = (__bf16*)(ws + WS_WT);
  float*  xap  = (float*)(ws + WS_XAP);
  float*  xdp  = (float*)(ws + WS_XDP);
  __bf16* ee0  = (__bf16*)(ws + WS_EE0);
  float*  cev  = (float*)(ws + WS_CE);
  float*  cnv  = (float*)(ws + WS_CN);
  int* csroff  = (int*)(ws + WS_CSROFF);
  int* csreid  = (int*)(ws + WS_CSREID);

  const int bid = blockIdx.x, tid = threadIdx.x;

  // ======================= PREP (block roles 0..43) =======================
  if (bid < 20) {
    // pack the 10 [128][128] weight blocks into wave-load order
    if (tid < 256) {
      const int m = bid >> 1, half = bid & 1;
      const int s = m / 5, t = m % 5;
      const float* src = (t < 3) ? (Weu + (size_t)(s*512 + t*128)*128)
                                 : (Wnu + (size_t)(s*384 + (t-3)*128)*128);
      for (int it = 0; it < 4; ++it) {
        int p = it*256 + tid;
        int mq = half*4 + (p >> 8);
        int c  = (p >> 6) & 3;
        int l  = p & 63;
        int fr = mq*16 + (l & 15);
        int kb = c*32 + (l >> 4)*8;
        __bf16* dst = &wt[m*16384 + ((mq*4 + c)*64 + l)*8];
        #pragma unroll
        for (int j = 0; j < 8; ++j)
          dst[j] = (__bf16)src[(kb + j)*128 + fr];
      }
    }
  } else if (bid < 28) {
    // per-graph: gg, ce/cn constants, CSR (deterministic). Scratch in pool.
    const int g = bid - 20;
    char* pb = (char*)pool;
    float* gg_sh = (float*)pb;              // 512 B
    int* dst_sh  = (int*)(pb + 512);        // 1024 B
    int* cnt_sh  = (int*)(pb + 1536);       // 256 B
    int* off_sh  = (int*)(pb + 1792);       // 260 B
    if (tid < 128) {
      float acc = bge[tid];
      for (int k = 0; k < 128; ++k)
        acc += u[g*128 + k] * Wge[k*128 + tid];
      gg_sh[tid] = leaky(acc);
    }
    if (tid < 256) dst_sh[tid] = eidx[g*512 + 256 + tid];
    __syncthreads();
    if (tid < 256) {
      const int s = tid >> 7, f = tid & 127;
      float ac = beu[s*128 + f];
      float an = bnu[s*128 + f];
      #pragma unroll 8
      for (int k = 0; k < 128; ++k) {
        float gk = gg_sh[k];
        ac += gk * Weu[(s*512 + 384 + k)*128 + f];
        an += gk * Wnu[(s*384 + 256 + k)*128 + f];
      }
      cev[(g*2 + s)*128 + f] = ac;
      cnv[(g*2 + s)*128 + f] = an;
    }
    if (tid < 64) {
      int c = 0;
      for (int e = 0; e < 256; ++e) c += (dst_sh[e] == tid) ? 1 : 0;
      cnt_sh[tid] = c;
    }
    __syncthreads();
    if (tid == 0) {
      int o = 0;
      for (int n = 0; n < 64; ++n) { off_sh[n] = o; o += cnt_sh[n]; }
      off_sh[64] = o;
    }
    __syncthreads();
    if (tid < 65) csroff[g*72 + tid] = off_sh[tid];
    if (tid < 64) {
      int o = off_sh[tid];
      for (int e = 0; e < 256; ++e)
        if (dst_sh[e] == tid) csreid[g*256 + (o++)] = e;
    }
  } else if (bid < 36) {
    // ee0 = leaky(edge_attr @ Wee + bee) via MFMA, one block-role per graph
    const int g = bid - 28;
    __bf16* s_a = pool;              // [256][LDE]
    __bf16* s_w = pool + 256*LDE;    // [128][LDE]
    if (tid < 256) {
      #pragma unroll
      for (int it = 0; it < 32; ++it) {
        int c = it*256 + tid;
        int row = c >> 5, f4 = (c & 31)*4;
        floatx4 v = *(const floatx4*)&ea[(size_t)(g*256 + row)*128 + f4];
        bf16x4 o;
        #pragma unroll
        for (int r = 0; r < 4; ++r) o[r] = (__bf16)v[r];
        *(bf16x4*)&s_a[row*LDE + f4] = o;
      }
      #pragma unroll 8
      for (int it = 0; it < 64; ++it) {
        int k = it*2 + (tid >> 7), f = tid & 127;
        s_w[f*LDE + k] = (__bf16)Wee[k*128 + f];
      }
    }
    __syncthreads();
    if (tid < 256) {
      const int w = tid >> 6, l = tid & 63, q = l >> 4, xn = l & 15;
      bf16x8 bea[4][4];
      #pragma unroll
      for (int t = 0; t < 4; ++t) {
        int e = w*64 + t*16 + xn;
        #pragma unroll
        for (int c = 0; c < 4; ++c)
          bea[t][c] = *(const bf16x8*)&s_a[e*LDE + c*32 + q*8];
      }
      #pragma unroll
      for (int m = 0; m < 8; ++m) {
        floatx4 acc[4];
        #pragma unroll
        for (int t = 0; t < 4; ++t) acc[t] = (floatx4)0.f;
        const int fr = m*16 + xn;
        #pragma unroll
        for (int c = 0; c < 4; ++c) {
          bf16x8 aw = *(const bf16x8*)&s_w[fr*LDE + c*32 + q*8];
          #pragma unroll
          for (int t = 0; t < 4; ++t) acc[t] = MFMA16(aw, bea[t][c], acc[t]);
        }
        const int f0 = m*16 + q*4;
        floatx4 b4 = *(const floatx4*)&bee[f0];
        #pragma unroll
        for (int t = 0; t < 4; ++t) {
          int e = w*64 + t*16 + xn;
          bf16x4 o;
          #pragma unroll
          for (int r = 0; r < 4; ++r) o[r] = (__bf16)leaky(acc[t][r] + b4[r]);
          *(bf16x4*)&ee0[(size_t)(g*256 + e)*128 + f0] = o;
        }
      }
    }
  } else if (bid < 44) {
    // xap = x @ Wne[0:128] + bne ; xdp = x @ Wne[128:256]  via MFMA, per graph
    const int g = bid - 36;
    __bf16* s_x  = pool;             // [64][LDE]
    __bf16* s_wa = pool + 64*LDE;    // [128][LDE]
    __bf16* s_wb = pool + 192*LDE;   // [128][LDE]
    if (tid < 256) {
      #pragma unroll
      for (int it = 0; it < 8; ++it) {
        int c = it*256 + tid;
        int row = c >> 5, f4 = (c & 31)*4;
        floatx4 v = *(const floatx4*)&x[(size_t)(g*64 + row)*128 + f4];
        bf16x4 o;
        #pragma unroll
        for (int r = 0; r < 4; ++r) o[r] = (__bf16)v[r];
        *(bf16x4*)&s_x[row*LDE + f4] = o;
      }
      #pragma unroll 8
      for (int it = 0; it < 64; ++it) {
        int k = it*2 + (tid >> 7), f = tid & 127;
        s_wa[f*LDE + k] = (__bf16)Wne[k*128 + f];
        s_wb[f*LDE + k] = (__bf16)Wne[(128 + k)*128 + f];
      }
    }
    __syncthreads();
    if (tid < 256) {
      const int w = tid >> 6, l = tid & 63, q = l >> 4, xn = l & 15;
      const int i = w*16 + xn;
      bf16x8 bx[4];
      #pragma unroll
      for (int c = 0; c < 4; ++c)
        bx[c] = *(const bf16x8*)&s_x[i*LDE + c*32 + q*8];
      #pragma unroll
      for (int m = 0; m < 8; ++m) {
        floatx4 aa = (floatx4)0.f, ab = (floatx4)0.f;
        const int fr = m*16 + xn;
        #pragma unroll
        for (int c = 0; c < 4; ++c) {
          bf16x8 aw = *(const bf16x8*)&s_wa[fr*LDE + c*32 + q*8];
          aa = MFMA16(aw, bx[c], aa);
        }
        #pragma unroll
        for (int c = 0; c < 4; ++c) {
          bf16x8 aw = *(const bf16x8*)&s_wb[fr*LDE + c*32 + q*8];
          ab = MFMA16(aw, bx[c], ab);
        }
        const int f0 = m*16 + q*4;
        floatx4 bn4 = *(const floatx4*)&bne[f0];
        floatx4 oa;
        #pragma unroll
        for (int r = 0; r < 4; ++r) oa[r] = aa[r] + bn4[r];
        *(floatx4*)&xap[(size_t)(g*64 + i)*128 + f0] = oa;
        *(floatx4*)&xdp[(size_t)(g*64 + i)*128 + f0] = ab;
      }
    }
  }

  __threadfence();
  cg::this_grid().sync();

  // ======================= MAIN (all 256 blocks) =======================
  const int w = tid >> 6, l = tid & 63;
  const int q = l >> 4, xn = l & 15;
  const int wp = w >> 1, mh = w & 1;      // edge-phase wave pair / m-half
  const int lane8 = l*8;                  // packed-fragment lane offset
  const int fme = w*16 + q*4;             // node-phase epilogue f-offset
  const int g = bid >> 5, dp = bid & 31;  // graph / d-pair

  if (tid < 65) s_off[tid] = csroff[g*72 + tid];
  if (tid < 256) s_eid[tid] = csreid[g*256 + tid];

  int mySrc[4], myDst[4];
  #pragma unroll
  for (int t = 0; t < 4; ++t) {
    int e = wp*64 + t*16 + xn;
    mySrc[t] = eidx[g*512 + e];
    myDst[t] = eidx[g*512 + 256 + e];
  }

  for (int r = 0; r < 2; ++r) {
    const int d = dp*2 + r;

    // node encoder: h[i][f] = leaky(xap[i][f] + xdp[d][f] + sp(d,i)*wsp[f])
    {
      const int f = tid & 127, ib = tid >> 7;   // ib in [0,4)
      float xdpv = xdp[(g*64 + d)*128 + f];
      float wspv = Wne[256*128 + f];
      #pragma unroll
      for (int j = 0; j < 16; ++j) {
        int i = ib + 4*j;
        float sp = spdist[(g*64 + d)*64 + i];
        float v = xap[(g*64 + i)*128 + f] + xdpv + sp*wspv;
        s_h[i*LDE + f] = (__bf16)leaky(v);
      }
    }
    // stage ee0 -> LDS (4096 chunks of 16B)
    #pragma unroll
    for (int it = 0; it < 8; ++it) {
      int c = it*512 + tid;
      int row = c >> 4, col = c & 15;
      *(bf16x8*)&s_ee[row*LDE + col*8] = *(const bf16x8*)&ee0[(g*256 + row)*128 + col*8];
    }
    __syncthreads();   // setup (covers s_off/s_eid on r=0)

    for (int s = 0; s < 2; ++s) {
      const __bf16* W1T = wt + (s*5 + 0)*16384;
      const __bf16* W2T = wt + (s*5 + 1)*16384;
      const __bf16* W3T = wt + (s*5 + 2)*16384;
      const __bf16* N1T = wt + (s*5 + 3)*16384;
      const __bf16* N2T = wt + (s*5 + 4)*16384;

      // step-start weight prefetch
      bf16x8 w2f[4], w3f[4], n1f[4], n2f[4], w1f[4][4];
      #pragma unroll
      for (int c = 0; c < 4; ++c) {
        w2f[c] = *(const bf16x8*)&W2T[(w*4 + c)*512 + lane8];
        w3f[c] = *(const bf16x8*)&W3T[(w*4 + c)*512 + lane8];
      }
      #pragma unroll
      for (int mm = 0; mm < 4; ++mm)
        #pragma unroll
        for (int c = 0; c < 4; ++c)
          w1f[mm][c] = *(const bf16x8*)&W1T[((mh*4 + mm)*4 + c)*512 + lane8];
      if (s == 0) {
        #pragma unroll
        for (int c = 0; c < 4; ++c) {
          n1f[c] = *(const bf16x8*)&N1T[(w*4 + c)*512 + lane8];
          n2f[c] = *(const bf16x8*)&N2T[(w*4 + c)*512 + lane8];
        }
      }

      // ======== segment A: ph1 (p2/p3) + ph2-MFMA ========
      {
        floatx4 ce4 = *(const floatx4*)&cev[(g*2 + s)*128 + fme];
        #pragma unroll
        for (int t = 0; t < 4; ++t) {
          const int i = t*16 + xn;
          floatx4 a2 = (floatx4)0.f, a3 = (floatx4)0.f;
          #pragma unroll
          for (int c = 0; c < 4; ++c) {
            bf16x8 bh = *(const bf16x8*)&s_h[i*LDE + c*32 + q*8];
            a2 = MFMA16(w2f[c], bh, a2);
            a3 = MFMA16(w3f[c], bh, a3);
          }
          bf16x4 o2, o3;
          #pragma unroll
          for (int r2 = 0; r2 < 4; ++r2) { o2[r2] = (__bf16)a2[r2]; o3[r2] = (__bf16)(a3[r2] + ce4[r2]); }
          *(bf16x4*)&s_p2[i*LDE + fme] = o2;
          *(bf16x4*)&s_p3[i*LDE + fme] = o3;
        }
      }
      floatx4 acc[4][4];
      {
        bf16x8 be[4][4];
        #pragma unroll
        for (int t = 0; t < 4; ++t) {
          int e = wp*64 + t*16 + xn;
          #pragma unroll
          for (int c = 0; c < 4; ++c)
            be[t][c] = *(const bf16x8*)&s_ee[e*LDE + c*32 + q*8];
        }
        #pragma unroll
        for (int mm = 0; mm < 4; ++mm) {
          #pragma unroll
          for (int t = 0; t < 4; ++t) acc[mm][t] = (floatx4)0.f;
          #pragma unroll
          for (int c = 0; c < 4; ++c) {
            #pragma unroll
            for (int t = 0; t < 4; ++t) acc[mm][t] = MFMA16(w1f[mm][c], be[t][c], acc[mm][t]);
          }
        }
      }
      __syncthreads();   // p2/p3 complete; all s_ee reads complete

      // ======== segment B: ph2 epilogue ========
      {
        #pragma unroll
        for (int mm = 0; mm < 4; ++mm) {
          const int m = mh*4 + mm;
          const int f0 = m*16 + q*4;
          #pragma unroll
          for (int t = 0; t < 4; ++t) {
            int e = wp*64 + t*16 + xn;
            bf16x4 old = *(const bf16x4*)&s_ee[e*LDE + f0];
            bf16x4 v2  = *(const bf16x4*)&s_p2[mySrc[t]*LDE + f0];
            bf16x4 v3  = *(const bf16x4*)&s_p3[myDst[t]*LDE + f0];
            bf16x4 res;
            #pragma unroll
            for (int r2 = 0; r2 < 4; ++r2) {
              float vv = acc[mm][t][r2] + (float)v2[r2] + (float)v3[r2];
              res[r2] = (__bf16)((float)old[r2] + leaky(vv));
            }
            *(bf16x4*)&s_ee[e*LDE + f0] = res;
          }
        }
      }
      __syncthreads();   // ee update complete

      if (s == 0) {
        // ======== segment C: ph3 (agg) + ph4's h@N1 ========
        floatx4 a4[4];
        {
          const int node = tid >> 3;
          const int fs = (tid & 7)*16;
          float av[16];
          #pragma unroll
          for (int j = 0; j < 16; ++j) av[j] = 0.f;
          const int b0 = s_off[node], b1 = s_off[node + 1];
          for (int idx = b0; idx < b1; ++idx) {
            int e = s_eid[idx];
            #pragma unroll
            for (int cc = 0; cc < 2; ++cc) {
              bf16x8 vv = *(const bf16x8*)&s_ee[e*LDE + fs + cc*8];
              #pragma unroll
              for (int j = 0; j < 8; ++j) av[cc*8 + j] += (float)vv[j];
            }
          }
          #pragma unroll
          for (int cc = 0; cc < 2; ++cc) {
            bf16x8 o;
            #pragma unroll
            for (int j = 0; j < 8; ++j) o[j] = (__bf16)av[cc*8 + j];
            *(bf16x8*)&s_p2[node*LDE + fs + cc*8] = o;
          }
          #pragma unroll
          for (int t = 0; t < 4; ++t) {
            const int i = t*16 + xn;
            floatx4 a = (floatx4)0.f;
            #pragma unroll
            for (int c = 0; c < 4; ++c) {
              bf16x8 bh = *(const bf16x8*)&s_h[i*LDE + c*32 + q*8];
              a = MFMA16(n1f[c], bh, a);
            }
            a4[t] = a;
          }
        }
        __syncthreads();   // agg complete; all s_h reads complete

        // ======== segment D: agg@N2 + h write ========
        {
          floatx4 cn4 = *(const floatx4*)&cnv[(g*2 + s)*128 + fme];
          #pragma unroll
          for (int t = 0; t < 4; ++t) {
            const int i = t*16 + xn;
            floatx4 a = a4[t];
            #pragma unroll
            for (int c = 0; c < 4; ++c) {
              bf16x8 bg = *(const bf16x8*)&s_p2[i*LDE + c*32 + q*8];
              a = MFMA16(n2f[c], bg, a);
            }
            bf16x4 old = *(const bf16x4*)&s_h[i*LDE + fme];
            bf16x4 res;
            #pragma unroll
            for (int r2 = 0; r2 < 4; ++r2)
              res[r2] = (__bf16)((float)old[r2] + leaky(a[r2] + cn4[r2]));
            *(bf16x4*)&s_h[i*LDE + fme] = res;
          }
        }
        __syncthreads();   // h update complete
      }
    }

    // ---- scores: out[g, e, d] = ee[e] . wscore + b  (fp32 output)
    {
      const int e = tid & 255, hh = tid >> 8;
      float acc2 = 0.f;
      #pragma unroll
      for (int c = 0; c < 8; ++c) {
        bf16x8 vv = *(const bf16x8*)&s_ee[e*LDE + hh*64 + c*8];
        #pragma unroll
        for (int j = 0; j < 8; ++j) acc2 += (float)vv[j] * wscore[hh*64 + c*8 + j];
      }
      if (hh == 1) s_sc[e] = acc2;
      __syncthreads();   // also isolates next r's s_ee/s_h writes from score reads
      if (hh == 0) out[g*16384 + e*64 + d] = acc2 + s_sc[e] + bscore[0];
    }
  }
}

extern "C" void kernel_launch(void* const* d_in, const int* in_sizes, int n_in,
                              void* d_out, int out_size, void* d_ws, size_t ws_size,
                              hipStream_t stream) {
  (void)in_sizes; (void)n_in; (void)out_size; (void)ws_size;
  const float* x   = (const float*)d_in[0];
  const float* ea  = (const float*)d_in[1];
  const float* u   = (const float*)d_in[2];
  const float* sp  = (const float*)d_in[3];
  const int*   ei  = (const int*)d_in[4];
  const float* Wne = (const float*)d_in[5];
  const float* bne = (const float*)d_in[6];
  const float* Wee = (const float*)d_in[7];
  const float* bee = (const float*)d_in[8];
  const float* Wge = (const float*)d_in[9];
  const float* bge = (const float*)d_in[10];
  const float* Weu = (const float*)d_in[11];
  const float* beu = (const float*)d_in[12];
  const float* Wnu = (const float*)d_in[13];
  const float* bnu = (const float*)d_in[14];
  const float* Wsc = (const float*)d_in[15];
  const float* bsc = (const float*)d_in[16];
  char* ws = (char*)d_ws;
  float* outp = (float*)d_out;

  void* args[] = { &x, &ea, &u, &sp, &ei, &Wne, &bne, &Wee, &bee, &Wge, &bge,
                   &Weu, &beu, &Wnu, &bnu, &Wsc, &bsc, &ws, &outp };
  hipLaunchCooperativeKernel(reinterpret_cast<void*>(mpn_fused),
                             dim3(256), dim3(512), args, 0, stream);
}

// Round 14
// 154.011 us; speedup vs baseline: 2.0983x; 2.0983x over previous
//
#include <hip/hip_runtime.h>
#include <hip/hip_bf16.h>

// MPNScoreModule: B=8 graphs, N=64 nodes, E=256 edges, L=128, S=2 steps.
// Round 14: REVERT to round 10 (best measured: total 153.2us, main 42.8us).
// Round-13 post-mortem: cooperative grid.sync() forced L2 writeback across
// non-coherent XCDs -> all ws reuse went HBM-cold (FETCH 4.5->65MB), 5x main
// regression. The two-kernel + L2-hot-ws design is structurally right.
// Main structure: prefetched A-frags (R8 packing), 4x B-reuse in edge phase,
// m=w node phases (R9 lesson), step-start prefetch (R10).

typedef __attribute__((ext_vector_type(8))) __bf16 bf16x8;
typedef __attribute__((ext_vector_type(4))) __bf16 bf16x4;
typedef __attribute__((ext_vector_type(4))) float  floatx4;

#define MFMA16(a, b, c) __builtin_amdgcn_mfma_f32_16x16x32_bf16((a), (b), (c), 0, 0, 0)

__device__ __forceinline__ float leaky(float x) { return x > 0.f ? x : 0.01f * x; }

// ---- workspace layout (bytes) ----
#define WS_WT     0          // bf16 [10][16384] PACKED weights: [m][(mq*4+c)*64+l][8]
#define WS_XAP    327680     // f32  [8][64][128]  x @ Wne[0:128] + b_node_enc
#define WS_XDP    589824     // f32  [8][64][128]  x @ Wne[128:256]
#define WS_EE0    851968     // bf16 [8][256][128] leaky(edge_attr @ Wee + b)
#define WS_CE     1376256    // f32  [8][2][128]   gg @ W4  + b_edge_upd
#define WS_CN     1384448    // f32  [8][2][128]   gg @ Wn3 + b_node_upd
#define WS_CSROFF 1392640    // int  [8][72]
#define WS_CSREID 1394944    // int  [8][256]
// end ~1.4 MB

#define LDE 140   // padded LDS row stride: 280 B = 70 dw = 6 mod 32 -> conflict-free

// ============================ prep kernel ============================
__global__ __launch_bounds__(256) void mpn_prep(
    const float* __restrict__ x,     // [8][64][128]
    const float* __restrict__ ea,    // [8][256][128]
    const float* __restrict__ u,     // [8][128]
    const int*   __restrict__ eidx,  // [8][2][256]
    const float* __restrict__ Wne,   // [257][128]
    const float* __restrict__ bne,   // [128]
    const float* __restrict__ Wee,   // [128][128]
    const float* __restrict__ bee,   // [128]
    const float* __restrict__ Wge,   // [128][128]
    const float* __restrict__ bge,   // [128]
    const float* __restrict__ Weu,   // [2][512][128]
    const float* __restrict__ beu,   // [2][128]
    const float* __restrict__ Wnu,   // [2][384][128]
    const float* __restrict__ bnu,   // [2][128]
    char* __restrict__ ws)
{
  __shared__ __align__(16) __bf16 smem[384 * LDE];

  const int b = blockIdx.x, tid = threadIdx.x;
  __bf16* wt  = (__bf16*)(ws + WS_WT);
  float*  xap = (float*)(ws + WS_XAP);
  float*  xdp = (float*)(ws + WS_XDP);
  __bf16* ee0 = (__bf16*)(ws + WS_EE0);
  float*  cev = (float*)(ws + WS_CE);
  float*  cnv = (float*)(ws + WS_CN);
  int* csroff = (int*)(ws + WS_CSROFF);
  int* csreid = (int*)(ws + WS_CSREID);

  if (b < 20) {
    // pack the 10 [128][128] weight blocks into wave-load order
    const int m = b >> 1, half = b & 1;
    const int s = m / 5, t = m % 5;
    const float* src = (t < 3) ? (Weu + (size_t)(s*512 + t*128)*128)
                               : (Wnu + (size_t)(s*384 + (t-3)*128)*128);
    for (int it = 0; it < 4; ++it) {
      int p = it*256 + tid;
      int mq = half*4 + (p >> 8);
      int c  = (p >> 6) & 3;
      int l  = p & 63;
      int fr = mq*16 + (l & 15);
      int kb = c*32 + (l >> 4)*8;
      __bf16* dst = &wt[m*16384 + ((mq*4 + c)*64 + l)*8];
      #pragma unroll
      for (int j = 0; j < 8; ++j)
        dst[j] = (__bf16)src[(kb + j)*128 + fr];
    }
  } else if (b < 28) {
    const int g = b - 20;
    __shared__ float gg_sh[128];
    __shared__ int dst_sh[256];
    __shared__ int cnt_sh[64];
    __shared__ int off_sh[65];
    if (tid < 128) {
      float acc = bge[tid];
      for (int k = 0; k < 128; ++k)
        acc += u[g*128 + k] * Wge[k*128 + tid];
      gg_sh[tid] = leaky(acc);
    }
    dst_sh[tid] = eidx[g*512 + 256 + tid];
    __syncthreads();
    {
      const int s = tid >> 7, f = tid & 127;
      float ac = beu[s*128 + f];
      float an = bnu[s*128 + f];
      #pragma unroll 8
      for (int k = 0; k < 128; ++k) {
        float gk = gg_sh[k];
        ac += gk * Weu[(s*512 + 384 + k)*128 + f];
        an += gk * Wnu[(s*384 + 256 + k)*128 + f];
      }
      cev[(g*2 + s)*128 + f] = ac;
      cnv[(g*2 + s)*128 + f] = an;
    }
    if (tid < 64) {
      int c = 0;
      for (int e = 0; e < 256; ++e) c += (dst_sh[e] == tid) ? 1 : 0;
      cnt_sh[tid] = c;
    }
    __syncthreads();
    if (tid == 0) {
      int o = 0;
      for (int n = 0; n < 64; ++n) { off_sh[n] = o; o += cnt_sh[n]; }
      off_sh[64] = o;
    }
    __syncthreads();
    if (tid < 65) csroff[g*72 + tid] = off_sh[tid];
    if (tid < 64) {
      int o = off_sh[tid];
      for (int e = 0; e < 256; ++e)
        if (dst_sh[e] == tid) csreid[g*256 + (o++)] = e;
    }
  } else if (b < 36) {
    // ee0 = leaky(edge_attr @ Wee + bee) via MFMA, one block per graph
    const int g = b - 28;
    __bf16* s_a = smem;
    __bf16* s_w = smem + 256*LDE;
    #pragma unroll
    for (int it = 0; it < 32; ++it) {
      int c = it*256 + tid;
      int row = c >> 5, f4 = (c & 31)*4;
      floatx4 v = *(const floatx4*)&ea[(size_t)(g*256 + row)*128 + f4];
      bf16x4 o;
      #pragma unroll
      for (int r = 0; r < 4; ++r) o[r] = (__bf16)v[r];
      *(bf16x4*)&s_a[row*LDE + f4] = o;
    }
    #pragma unroll 8
    for (int it = 0; it < 64; ++it) {
      int k = it*2 + (tid >> 7), f = tid & 127;
      s_w[f*LDE + k] = (__bf16)Wee[k*128 + f];
    }
    __syncthreads();
    const int w = tid >> 6, l = tid & 63, q = l >> 4, xn = l & 15;
    bf16x8 bea[4][4];
    #pragma unroll
    for (int t = 0; t < 4; ++t) {
      int e = w*64 + t*16 + xn;
      #pragma unroll
      for (int c = 0; c < 4; ++c)
        bea[t][c] = *(const bf16x8*)&s_a[e*LDE + c*32 + q*8];
    }
    #pragma unroll
    for (int m = 0; m < 8; ++m) {
      floatx4 acc[4];
      #pragma unroll
      for (int t = 0; t < 4; ++t) acc[t] = (floatx4)0.f;
      const int fr = m*16 + xn;
      #pragma unroll
      for (int c = 0; c < 4; ++c) {
        bf16x8 aw = *(const bf16x8*)&s_w[fr*LDE + c*32 + q*8];
        #pragma unroll
        for (int t = 0; t < 4; ++t) acc[t] = MFMA16(aw, bea[t][c], acc[t]);
      }
      const int f0 = m*16 + q*4;
      floatx4 b4 = *(const floatx4*)&bee[f0];
      #pragma unroll
      for (int t = 0; t < 4; ++t) {
        int e = w*64 + t*16 + xn;
        bf16x4 o;
        #pragma unroll
        for (int r = 0; r < 4; ++r) o[r] = (__bf16)leaky(acc[t][r] + b4[r]);
        *(bf16x4*)&ee0[(size_t)(g*256 + e)*128 + f0] = o;
      }
    }
  } else {
    // xap = x @ Wne[0:128] + bne ; xdp = x @ Wne[128:256]  via MFMA, per graph
    const int g = b - 36;
    __bf16* s_x  = smem;
    __bf16* s_wa = smem + 64*LDE;
    __bf16* s_wb = smem + 192*LDE;
    #pragma unroll
    for (int it = 0; it < 8; ++it) {
      int c = it*256 + tid;
      int row = c >> 5, f4 = (c & 31)*4;
      floatx4 v = *(const floatx4*)&x[(size_t)(g*64 + row)*128 + f4];
      bf16x4 o;
      #pragma unroll
      for (int r = 0; r < 4; ++r) o[r] = (__bf16)v[r];
      *(bf16x4*)&s_x[row*LDE + f4] = o;
    }
    #pragma unroll 8
    for (int it = 0; it < 64; ++it) {
      int k = it*2 + (tid >> 7), f = tid & 127;
      s_wa[f*LDE + k] = (__bf16)Wne[k*128 + f];
      s_wb[f*LDE + k] = (__bf16)Wne[(128 + k)*128 + f];
    }
    __syncthreads();
    const int w = tid >> 6, l = tid & 63, q = l >> 4, xn = l & 15;
    const int i = w*16 + xn;
    bf16x8 bx[4];
    #pragma unroll
    for (int c = 0; c < 4; ++c)
      bx[c] = *(const bf16x8*)&s_x[i*LDE + c*32 + q*8];
    #pragma unroll
    for (int m = 0; m < 8; ++m) {
      floatx4 aa = (floatx4)0.f, ab = (floatx4)0.f;
      const int fr = m*16 + xn;
      #pragma unroll
      for (int c = 0; c < 4; ++c) {
        bf16x8 aw = *(const bf16x8*)&s_wa[fr*LDE + c*32 + q*8];
        aa = MFMA16(aw, bx[c], aa);
      }
      #pragma unroll
      for (int c = 0; c < 4; ++c) {
        bf16x8 aw = *(const bf16x8*)&s_wb[fr*LDE + c*32 + q*8];
        ab = MFMA16(aw, bx[c], ab);
      }
      const int f0 = m*16 + q*4;
      floatx4 bn4 = *(const floatx4*)&bne[f0];
      floatx4 oa;
      #pragma unroll
      for (int r = 0; r < 4; ++r) oa[r] = aa[r] + bn4[r];
      *(floatx4*)&xap[(size_t)(g*64 + i)*128 + f0] = oa;
      *(floatx4*)&xdp[(size_t)(g*64 + i)*128 + f0] = ab;
    }
  }
}

// ============================ main kernel ============================
// 512 threads = 8 waves. Phases 1/4: wave w owns f-slice m=w for all rows
// (4 weight frags/matrix in registers, prefetched at step start).
// Phase 2: wave-pair wp owns edges wp*64..+63, mh = w&1 splits m (B-frags
// reused 4x); its 16 W1 frags also prefetched at step start.
__global__ __launch_bounds__(512, 2) void mpn_main(
    const float* __restrict__ spdist,  // [8][64][64]
    const int*   __restrict__ eidx,    // [8][2][256]
    const float* __restrict__ Wne,     // row 256 = spdist weight
    const float* __restrict__ wscore,  // [128]
    const float* __restrict__ bscore,  // [1]
    const char* __restrict__ ws,
    float* __restrict__ out)           // [8][256][64]  (g*16384 + e*64 + d), fp32
{
  __shared__ __align__(16) __bf16 s_ee[256*LDE];   // edge state
  __shared__ __align__(16) __bf16 s_h [64*LDE];    // node state
  __shared__ __align__(16) __bf16 s_p2[64*LDE];    // h@W2 (reused as agg)
  __shared__ __align__(16) __bf16 s_p3[64*LDE];    // h@W3 + ce
  __shared__ int s_off[65];
  __shared__ int s_eid[256];
  __shared__ float s_sc[256];

  const __bf16* wt  = (const __bf16*)(ws + WS_WT);
  const float*  xap = (const float*)(ws + WS_XAP);
  const float*  xdp = (const float*)(ws + WS_XDP);
  const __bf16* ee0 = (const __bf16*)(ws + WS_EE0);
  const float*  cev = (const float*)(ws + WS_CE);
  const float*  cnv = (const float*)(ws + WS_CN);
  const int* csroff = (const int*)(ws + WS_CSROFF);
  const int* csreid = (const int*)(ws + WS_CSREID);

  const int tid = threadIdx.x;
  const int w = tid >> 6, l = tid & 63;
  const int q = l >> 4, xn = l & 15;
  const int wp = w >> 1, mh = w & 1;      // phase-2 wave pair / m-half
  const int lane8 = l*8;                  // packed-fragment lane offset
  const int fme = w*16 + q*4;             // phase-1/4 epilogue f-offset
  const int g = blockIdx.x >> 6, d = blockIdx.x & 63;

  if (tid < 65) s_off[tid] = csroff[g*72 + tid];
  if (tid < 256) s_eid[tid] = csreid[g*256 + tid];

  // node encoder: h[i][f] = leaky(xap[i][f] + xdp[d][f] + sp(d,i)*wsp[f])
  {
    const int f = tid & 127, ib = tid >> 7;   // ib in [0,4)
    float xdpv = xdp[(g*64 + d)*128 + f];
    float wspv = Wne[256*128 + f];
    #pragma unroll
    for (int j = 0; j < 16; ++j) {
      int i = ib + 4*j;
      float sp = spdist[(g*64 + d)*64 + i];
      float v = xap[(g*64 + i)*128 + f] + xdpv + sp*wspv;
      s_h[i*LDE + f] = (__bf16)leaky(v);
    }
  }
  // stage ee0 -> LDS (4096 chunks of 16B)
  #pragma unroll
  for (int it = 0; it < 8; ++it) {
    int c = it*512 + tid;
    int row = c >> 4, col = c & 15;
    *(bf16x8*)&s_ee[row*LDE + col*8] = *(const bf16x8*)&ee0[(g*256 + row)*128 + col*8];
  }

  // phase-2 per-lane src/dst (round-8 mapping: e = wp*64 + t*16 + xn)
  int mySrc[4], myDst[4];
  #pragma unroll
  for (int t = 0; t < 4; ++t) {
    int e = wp*64 + t*16 + xn;
    mySrc[t] = eidx[g*512 + e];
    myDst[t] = eidx[g*512 + 256 + e];
  }
  __syncthreads();

  for (int s = 0; s < 2; ++s) {
    const __bf16* W1T = wt + (s*5 + 0)*16384;
    const __bf16* W2T = wt + (s*5 + 1)*16384;
    const __bf16* W3T = wt + (s*5 + 2)*16384;
    const __bf16* N1T = wt + (s*5 + 3)*16384;
    const __bf16* N2T = wt + (s*5 + 4)*16384;

    // ---- step-start weight prefetch (all L2 loads issued before any compute)
    bf16x8 w2f[4], w3f[4], n1f[4], n2f[4], w1f[4][4];
    #pragma unroll
    for (int c = 0; c < 4; ++c) {
      w2f[c] = *(const bf16x8*)&W2T[(w*4 + c)*512 + lane8];
      w3f[c] = *(const bf16x8*)&W3T[(w*4 + c)*512 + lane8];
    }
    #pragma unroll
    for (int mm = 0; mm < 4; ++mm)
      #pragma unroll
      for (int c = 0; c < 4; ++c)
        w1f[mm][c] = *(const bf16x8*)&W1T[((mh*4 + mm)*4 + c)*512 + lane8];
    if (s == 0) {
      #pragma unroll
      for (int c = 0; c < 4; ++c) {
        n1f[c] = *(const bf16x8*)&N1T[(w*4 + c)*512 + lane8];
        n2f[c] = *(const bf16x8*)&N2T[(w*4 + c)*512 + lane8];
      }
    }

    // ---- phase 1: s_p2 = h@W2 ; s_p3 = h@W3 + ce  (wave w: all nodes, f-slice fme)
    {
      floatx4 ce4 = *(const floatx4*)&cev[(g*2 + s)*128 + fme];
      #pragma unroll
      for (int t = 0; t < 4; ++t) {
        const int i = t*16 + xn;
        floatx4 a2 = (floatx4)0.f, a3 = (floatx4)0.f;
        #pragma unroll
        for (int c = 0; c < 4; ++c) {
          bf16x8 bh = *(const bf16x8*)&s_h[i*LDE + c*32 + q*8];
          a2 = MFMA16(w2f[c], bh, a2);
          a3 = MFMA16(w3f[c], bh, a3);
        }
        bf16x4 o2, o3;
        #pragma unroll
        for (int r = 0; r < 4; ++r) { o2[r] = (__bf16)a2[r]; o3[r] = (__bf16)(a3[r] + ce4[r]); }
        *(bf16x4*)&s_p2[i*LDE + fme] = o2;
        *(bf16x4*)&s_p3[i*LDE + fme] = o3;
      }
    }
    __syncthreads();

    // ---- phase 2: ee += leaky(ee@W1 + p2[src] + p3[dst])  (round-8 mapping)
    {
      bf16x8 be[4][4];
      #pragma unroll
      for (int t = 0; t < 4; ++t) {
        int e = wp*64 + t*16 + xn;
        #pragma unroll
        for (int c = 0; c < 4; ++c)
          be[t][c] = *(const bf16x8*)&s_ee[e*LDE + c*32 + q*8];
      }
      __syncthreads();   // snapshot complete before any pair-member writes
      #pragma unroll
      for (int mm = 0; mm < 4; ++mm) {
        const int m = mh*4 + mm;
        floatx4 acc[4];
        #pragma unroll
        for (int t = 0; t < 4; ++t) acc[t] = (floatx4)0.f;
        #pragma unroll
        for (int c = 0; c < 4; ++c) {
          #pragma unroll
          for (int t = 0; t < 4; ++t) acc[t] = MFMA16(w1f[mm][c], be[t][c], acc[t]);
        }
        const int f0 = m*16 + q*4;
        #pragma unroll
        for (int t = 0; t < 4; ++t) {
          int e = wp*64 + t*16 + xn;
          bf16x4 old = *(const bf16x4*)&s_ee[e*LDE + f0];
          bf16x4 v2  = *(const bf16x4*)&s_p2[mySrc[t]*LDE + f0];
          bf16x4 v3  = *(const bf16x4*)&s_p3[myDst[t]*LDE + f0];
          bf16x4 res;
          #pragma unroll
          for (int r = 0; r < 4; ++r) {
            float vv = acc[t][r] + (float)v2[r] + (float)v3[r];
            res[r] = (__bf16)((float)old[r] + leaky(vv));
          }
          *(bf16x4*)&s_ee[e*LDE + f0] = res;
        }
      }
    }
    __syncthreads();

    if (s == 0) {  // last step's node update is unused -> skip
      // ---- phase 3: agg = segment_sum(ee, dst) -> s_p2 (bf16). 8 thr/node.
      {
        const int node = tid >> 3;
        const int fs = (tid & 7)*16;
        float av[16];
        #pragma unroll
        for (int j = 0; j < 16; ++j) av[j] = 0.f;
        const int b0 = s_off[node], b1 = s_off[node + 1];
        for (int idx = b0; idx < b1; ++idx) {
          int e = s_eid[idx];
          #pragma unroll
          for (int cc = 0; cc < 2; ++cc) {
            bf16x8 vv = *(const bf16x8*)&s_ee[e*LDE + fs + cc*8];
            #pragma unroll
            for (int j = 0; j < 8; ++j) av[cc*8 + j] += (float)vv[j];
          }
        }
        #pragma unroll
        for (int cc = 0; cc < 2; ++cc) {
          bf16x8 o;
          #pragma unroll
          for (int j = 0; j < 8; ++j) o[j] = (__bf16)av[cc*8 + j];
          *(bf16x8*)&s_p2[node*LDE + fs + cc*8] = o;
        }
      }
      __syncthreads();
      // ---- phase 4: h += leaky(h@Wn1 + agg@Wn2 + cn)  (wave w: all nodes, f-slice fme)
      {
        floatx4 acc4[4];
        #pragma unroll
        for (int t = 0; t < 4; ++t) {
          const int i = t*16 + xn;
          floatx4 a = (floatx4)0.f;
          #pragma unroll
          for (int c = 0; c < 4; ++c) {
            bf16x8 bh = *(const bf16x8*)&s_h[i*LDE + c*32 + q*8];
            a = MFMA16(n1f[c], bh, a);
          }
          #pragma unroll
          for (int c = 0; c < 4; ++c) {
            bf16x8 bg = *(const bf16x8*)&s_p2[i*LDE + c*32 + q*8];
            a = MFMA16(n2f[c], bg, a);
          }
          acc4[t] = a;
        }
        __syncthreads();   // all k-reads of s_h complete before any f-slice write
        floatx4 cn4 = *(const floatx4*)&cnv[(g*2 + s)*128 + fme];
        #pragma unroll
        for (int t = 0; t < 4; ++t) {
          const int i = t*16 + xn;
          bf16x4 old = *(const bf16x4*)&s_h[i*LDE + fme];
          bf16x4 res;
          #pragma unroll
          for (int r = 0; r < 4; ++r)
            res[r] = (__bf16)((float)old[r] + leaky(acc4[t][r] + cn4[r]));
          *(bf16x4*)&s_h[i*LDE + fme] = res;
        }
      }
      __syncthreads();
    }
  }

  // ---- scores: out[g, e, d] = ee[e] . wscore + b  (fp32 output)
  {
    const int e = tid & 255, hh = tid >> 8;
    float acc = 0.f;
    #pragma unroll
    for (int c = 0; c < 8; ++c) {
      bf16x8 vv = *(const bf16x8*)&s_ee[e*LDE + hh*64 + c*8];
      #pragma unroll
      for (int j = 0; j < 8; ++j) acc += (float)vv[j] * wscore[hh*64 + c*8 + j];
    }
    if (hh == 1) s_sc[e] = acc;
    __syncthreads();
    if (hh == 0) out[g*16384 + e*64 + d] = acc + s_sc[e] + bscore[0];
  }
}

extern "C" void kernel_launch(void* const* d_in, const int* in_sizes, int n_in,
                              void* d_out, int out_size, void* d_ws, size_t ws_size,
                              hipStream_t stream) {
  (void)in_sizes; (void)n_in; (void)out_size; (void)ws_size;
  const float* x   = (const float*)d_in[0];
  const float* ea  = (const float*)d_in[1];
  const float* u   = (const float*)d_in[2];
  const float* sp  = (const float*)d_in[3];
  const int*   ei  = (const int*)d_in[4];
  const float* Wne = (const float*)d_in[5];
  const float* bne = (const float*)d_in[6];
  const float* Wee = (const float*)d_in[7];
  const float* bee = (const float*)d_in[8];
  const float* Wge = (const float*)d_in[9];
  const float* bge = (const float*)d_in[10];
  const float* Weu = (const float*)d_in[11];
  const float* beu = (const float*)d_in[12];
  const float* Wnu = (const float*)d_in[13];
  const float* bnu = (const float*)d_in[14];
  const float* Wsc = (const float*)d_in[15];
  const float* bsc = (const float*)d_in[16];
  char* ws = (char*)d_ws;

  hipLaunchKernelGGL(mpn_prep, dim3(44), dim3(256), 0, stream,
                     x, ea, u, ei, Wne, bne, Wee, bee, Wge, bge, Weu, beu, Wnu, bnu, ws);
  hipLaunchKernelGGL(mpn_main, dim3(512), dim3(512), 0, stream,
                     sp, ei, Wne, Wsc, bsc, (const char*)ws, (float*)d_out);
}